// Round 4
// baseline (680.252 us; speedup 1.0000x reference)
//
#include <hip/hip_runtime.h>
#include <math.h>

#define NN 50000

typedef unsigned short u16;
typedef unsigned int u32;

__device__ __forceinline__ u16 f2bf(float f) {
    u32 u = __float_as_uint(f);
    u32 r = (u + 0x7FFFu + ((u >> 16) & 1u)) >> 16;
    return (u16)r;
}
__device__ __forceinline__ float bf2f_lo(u32 v) { return __uint_as_float(v << 16); }
__device__ __forceinline__ float bf2f_hi(u32 v) { return __uint_as_float(v & 0xFFFF0000u); }

// ---------------- CSR build ----------------
__global__ void k_counti(const int* __restrict__ dst, int E, int* __restrict__ cnt) {
    int i = blockIdx.x * 256 + threadIdx.x;
    if (i < E) atomicAdd(&cnt[dst[i]], 1);
}

__global__ void k_dis(const int* __restrict__ cnt, float* __restrict__ dis, int n) {
    int i = blockIdx.x * 256 + threadIdx.x;
    if (i < n) dis[i] = rsqrtf((float)cnt[i] + 1.0f);
}

__global__ void k_scan(const int* __restrict__ cnt, int* __restrict__ rowstart, int n, int E) {
    __shared__ int ssum[1024];
    int t = threadIdx.x;
    const int CH = (n + 1023) / 1024;
    int beg = t * CH, end = min(beg + CH, n);
    int s = 0;
    for (int i = beg; i < end; i++) s += cnt[i];
    ssum[t] = s; __syncthreads();
    int v = s;
    for (int off = 1; off < 1024; off <<= 1) {
        int o = (t >= off) ? ssum[t - off] : 0;
        __syncthreads();
        v += o; ssum[t] = v;
        __syncthreads();
    }
    int base = v - s;
    for (int i = beg; i < end; i++) { rowstart[i] = base; base += cnt[i]; }
    if (t == 1023) rowstart[n] = E;
}

__global__ void k_fill(const int* __restrict__ src, const int* __restrict__ dst, int E,
                       const int* __restrict__ rowstart, int* __restrict__ cur,
                       int* __restrict__ adj) {
    int e = blockIdx.x * 256 + threadIdx.x;
    if (e < E) {
        int d = dst[e];
        int p = atomicAdd(&cur[d], 1);
        adj[rowstart[d] + p] = src[e];
    }
}

// ---------------- layer-1 front ----------------
__global__ void k_pre3(const float* __restrict__ x, const float* __restrict__ dis,
                       float* __restrict__ p, int n3) {
    int i = blockIdx.x * 256 + threadIdx.x;
    if (i < n3) p[i] = dis[i / 3] * x[i];
}

__global__ void k_gather3(const int* __restrict__ rowstart, const int* __restrict__ adj,
                          const float* __restrict__ p, const float* __restrict__ dis,
                          float* __restrict__ z, int n) {
    int row = blockIdx.x * 256 + threadIdx.x;
    if (row >= n) return;
    float a0 = p[row * 3], a1 = p[row * 3 + 1], a2 = p[row * 3 + 2];
    int beg = rowstart[row], end = rowstart[row + 1];
    for (int j = beg; j < end; j++) {
        int s = adj[j];
        a0 += p[s * 3]; a1 += p[s * 3 + 1]; a2 += p[s * 3 + 2];
    }
    float dv = dis[row];
    z[row * 3] = dv * a0; z[row * 3 + 1] = dv * a1; z[row * 3 + 2] = dv * a2;
}

// ---------------- bf16 gather (64 features): 16 lanes/row, 16 rows/block ----------------
__global__ __launch_bounds__(256) void k_gather64_bf16(const int* __restrict__ rowstart,
        const int* __restrict__ adj, const u16* __restrict__ pb,
        const float* __restrict__ dis, float* __restrict__ z, int n) {
    int row = blockIdx.x * 16 + (threadIdx.x >> 4);
    int lane = threadIdx.x & 15;
    if (row >= n) return;
    uint2 v = *((const uint2*)(pb + ((size_t)row << 6)) + lane);
    float a0 = bf2f_lo(v.x), a1 = bf2f_hi(v.x), a2 = bf2f_lo(v.y), a3 = bf2f_hi(v.y);
    int beg = rowstart[row], end = rowstart[row + 1];
    int j = beg;
    for (; j + 3 < end; j += 4) {
        int s0 = adj[j], s1 = adj[j + 1], s2 = adj[j + 2], s3 = adj[j + 3];
        uint2 v0 = *((const uint2*)(pb + ((size_t)s0 << 6)) + lane);
        uint2 v1 = *((const uint2*)(pb + ((size_t)s1 << 6)) + lane);
        uint2 v2 = *((const uint2*)(pb + ((size_t)s2 << 6)) + lane);
        uint2 v3 = *((const uint2*)(pb + ((size_t)s3 << 6)) + lane);
        a0 += (bf2f_lo(v0.x) + bf2f_lo(v1.x)) + (bf2f_lo(v2.x) + bf2f_lo(v3.x));
        a1 += (bf2f_hi(v0.x) + bf2f_hi(v1.x)) + (bf2f_hi(v2.x) + bf2f_hi(v3.x));
        a2 += (bf2f_lo(v0.y) + bf2f_lo(v1.y)) + (bf2f_lo(v2.y) + bf2f_lo(v3.y));
        a3 += (bf2f_hi(v0.y) + bf2f_hi(v1.y)) + (bf2f_hi(v2.y) + bf2f_hi(v3.y));
    }
    for (; j < end; j++) {
        uint2 v0 = *((const uint2*)(pb + ((size_t)adj[j] << 6)) + lane);
        a0 += bf2f_lo(v0.x); a1 += bf2f_hi(v0.x);
        a2 += bf2f_lo(v0.y); a3 += bf2f_hi(v0.y);
    }
    float dv = dis[row];
    ((float4*)z)[(size_t)row * 16 + lane] = make_float4(a0 * dv, a1 * dv, a2 * dv, a3 * dv);
}

__global__ void k_gather1_final(const int* __restrict__ rowstart, const int* __restrict__ adj,
                                const float* __restrict__ q, const float* __restrict__ dis,
                                const float* __restrict__ b4, float* __restrict__ out, int n) {
    int row = blockIdx.x * 256 + threadIdx.x;
    if (row >= n) return;
    float acc = q[row];
    int beg = rowstart[row], end = rowstart[row + 1];
    for (int j = beg; j < end; j++) acc += q[adj[j]];
    float v = dis[row] * acc + b4[0];
    out[row] = 1.f / (1.f + expf(-v));
}

// ---------------- GEMM (IN=64, 64x64 per block, col-blocked) + fused stats, bf16 out ----------------
// grid: (ceil(n/64), NCB). W row stride wrow4 (float4s); output stride tstride (u16);
// stats: st[cb*64+c], st[F + cb*64+c].
__global__ __launch_bounds__(256) void k_gemm64c(const float* __restrict__ z,
        const float* __restrict__ W, int wrow4, u16* __restrict__ t, int tstride,
        double* __restrict__ st, int F, int n) {
    __shared__ __align__(16) float sH[64 * 68];   // 17408 B
    __shared__ __align__(16) float sW[64 * 64];   // 16384 B
    const int tid = threadIdx.x;
    const int r0 = blockIdx.x * 64;
    const int cb = blockIdx.y;
    {
        const float4* Z4 = (const float4*)z;
        for (int i = tid; i < 64 * 16; i += 256) {
            int r = i >> 4, c = i & 15;
            float4 v = (r0 + r < n) ? Z4[(size_t)(r0 + r) * 16 + c]
                                    : make_float4(0.f, 0.f, 0.f, 0.f);
            *(float4*)&sH[r * 68 + c * 4] = v;
        }
        const float4* Wsrc = (const float4*)W;
        float4* sW4d = (float4*)sW;
        for (int i = tid; i < 64 * 16; i += 256) {
            int k = i >> 4, c = i & 15;
            sW4d[k * 16 + c] = Wsrc[(size_t)k * wrow4 + cb * 16 + c];
        }
    }
    __syncthreads();
    const int tx = tid & 15, ty = tid >> 4;
    float4 acc[4];
#pragma unroll
    for (int r = 0; r < 4; r++) acc[r] = make_float4(0.f, 0.f, 0.f, 0.f);
    const float4* sW4 = (const float4*)sW;
#pragma unroll
    for (int k4 = 0; k4 < 16; k4++) {
        float4 wv0 = sW4[(k4 * 4 + 0) * 16 + tx];
        float4 wv1 = sW4[(k4 * 4 + 1) * 16 + tx];
        float4 wv2 = sW4[(k4 * 4 + 2) * 16 + tx];
        float4 wv3 = sW4[(k4 * 4 + 3) * 16 + tx];
#pragma unroll
        for (int r = 0; r < 4; r++) {
            float4 hv = *(const float4*)&sH[(ty * 4 + r) * 68 + k4 * 4];
            acc[r].x += hv.x * wv0.x + hv.y * wv1.x + hv.z * wv2.x + hv.w * wv3.x;
            acc[r].y += hv.x * wv0.y + hv.y * wv1.y + hv.z * wv2.y + hv.w * wv3.y;
            acc[r].z += hv.x * wv0.z + hv.y * wv1.z + hv.z * wv2.z + hv.w * wv3.z;
            acc[r].w += hv.x * wv0.w + hv.y * wv1.w + hv.z * wv2.w + hv.w * wv3.w;
        }
    }
    // store bf16
#pragma unroll
    for (int r = 0; r < 4; r++) {
        int row = r0 + ty * 4 + r;
        if (row < n) {
            uint2 o;
            o.x = (u32)f2bf(acc[r].x) | ((u32)f2bf(acc[r].y) << 16);
            o.y = (u32)f2bf(acc[r].z) | ((u32)f2bf(acc[r].w) << 16);
            *(uint2*)&t[(size_t)row * tstride + cb * 64 + tx * 4] = o;
        }
    }
    // fused BN stats (pad rows contribute zero)
    __syncthreads();
    double* redS = (double*)sH;           // 16*64 doubles = 8 KB
    double* redQ = (double*)sW;           // 16*64 doubles = 8 KB
    double s0 = 0, s1 = 0, s2 = 0, s3 = 0, q0 = 0, q1 = 0, q2 = 0, q3 = 0;
#pragma unroll
    for (int r = 0; r < 4; r++) {
        s0 += acc[r].x; q0 += (double)acc[r].x * acc[r].x;
        s1 += acc[r].y; q1 += (double)acc[r].y * acc[r].y;
        s2 += acc[r].z; q2 += (double)acc[r].z * acc[r].z;
        s3 += acc[r].w; q3 += (double)acc[r].w * acc[r].w;
    }
    int base = ty * 64 + tx * 4;
    redS[base + 0] = s0; redS[base + 1] = s1; redS[base + 2] = s2; redS[base + 3] = s3;
    redQ[base + 0] = q0; redQ[base + 1] = q1; redQ[base + 2] = q2; redQ[base + 3] = q3;
    __syncthreads();
    if (ty == 0) {
#pragma unroll
        for (int jj = 0; jj < 4; jj++) {
            int c = tx * 4 + jj;
            double S = 0, Q = 0;
            for (int g = 0; g < 16; g++) { S += redS[g * 64 + c]; Q += redQ[g * 64 + c]; }
            atomicAdd(&st[cb * 64 + c], S);
            atomicAdd(&st[F + cb * 64 + c], Q);
        }
    }
}

// GEMM IN=3 -> OUT=64 with fused stats, bf16 out
__global__ __launch_bounds__(256) void k_gemm3_stats(const float* __restrict__ z,
        const float* __restrict__ W, u16* __restrict__ t,
        double* __restrict__ st, int n) {
    __shared__ float sH[64 * 4];
    __shared__ float sW[3 * 64];
    __shared__ double red[2 * 16 * 64];
    const int tid = threadIdx.x;
    const int r0 = blockIdx.x * 64;
    for (int i = tid; i < 192; i += 256) {
        int r = i / 3, c = i - r * 3;
        sH[r * 4 + c] = (r0 + r < n) ? z[(size_t)(r0 + r) * 3 + c] : 0.f;
    }
    if (tid < 48) ((float4*)sW)[tid] = ((const float4*)W)[tid];
    __syncthreads();
    const int tx = tid & 15, ty = tid >> 4;
    float4 acc[4];
#pragma unroll
    for (int r = 0; r < 4; r++) acc[r] = make_float4(0.f, 0.f, 0.f, 0.f);
    const float4* sW4 = (const float4*)sW;
#pragma unroll
    for (int k = 0; k < 3; k++) {
        float4 wv = sW4[k * 16 + tx];
#pragma unroll
        for (int r = 0; r < 4; r++) {
            float hs = sH[(ty * 4 + r) * 4 + k];
            acc[r].x += hs * wv.x; acc[r].y += hs * wv.y;
            acc[r].z += hs * wv.z; acc[r].w += hs * wv.w;
        }
    }
#pragma unroll
    for (int r = 0; r < 4; r++) {
        int row = r0 + ty * 4 + r;
        if (row < n) {
            uint2 o;
            o.x = (u32)f2bf(acc[r].x) | ((u32)f2bf(acc[r].y) << 16);
            o.y = (u32)f2bf(acc[r].z) | ((u32)f2bf(acc[r].w) << 16);
            *(uint2*)&t[(size_t)row * 64 + tx * 4] = o;
        }
    }
    double* redS = red;
    double* redQ = red + 16 * 64;
    double s0 = 0, s1 = 0, s2 = 0, s3 = 0, q0 = 0, q1 = 0, q2 = 0, q3 = 0;
#pragma unroll
    for (int r = 0; r < 4; r++) {
        s0 += acc[r].x; q0 += (double)acc[r].x * acc[r].x;
        s1 += acc[r].y; q1 += (double)acc[r].y * acc[r].y;
        s2 += acc[r].z; q2 += (double)acc[r].z * acc[r].z;
        s3 += acc[r].w; q3 += (double)acc[r].w * acc[r].w;
    }
    int base = ty * 64 + tx * 4;
    redS[base + 0] = s0; redS[base + 1] = s1; redS[base + 2] = s2; redS[base + 3] = s3;
    redQ[base + 0] = q0; redQ[base + 1] = q1; redQ[base + 2] = q2; redQ[base + 3] = q3;
    __syncthreads();
    if (ty == 0) {
#pragma unroll
        for (int jj = 0; jj < 4; jj++) {
            int c = tx * 4 + jj;
            double S = 0, Q = 0;
            for (int g = 0; g < 16; g++) { S += redS[g * 64 + c]; Q += redQ[g * 64 + c]; }
            atomicAdd(&st[c], S);
            atomicAdd(&st[64 + c], Q);
        }
    }
}

template<int F>
__global__ void k_bn_fin(double* __restrict__ stats, const float* __restrict__ g,
                         const float* __restrict__ be, int n) {
    int f = threadIdx.x;
    if (f >= F) return;
    double mean = stats[f] / n;
    double var = stats[F + f] / n - mean * mean;
    if (var < 0.0) var = 0.0;
    double mult = (double)g[f] / sqrt(var + 1e-5);
    stats[2 * F + f] = mult;
    stats[3 * F + f] = (double)be[f] - mult * mean;
}

// p_bf16 = dis[v] * lrelu(mult*t_bf16 + add)   (F=64)
__global__ void k_apply64(const u16* __restrict__ t, const float* __restrict__ dis,
                          const double* __restrict__ st, u16* __restrict__ p, int n) {
    int idx = blockIdx.x * 256 + threadIdx.x;   // quad index
    if (idx >= n * 16) return;
    int row = idx >> 4, c = (idx & 15) * 4;
    uint2 v = ((const uint2*)t)[idx];
    float f0 = bf2f_lo(v.x), f1 = bf2f_hi(v.x), f2 = bf2f_lo(v.y), f3 = bf2f_hi(v.y);
    float m0 = (float)st[128 + c], m1 = (float)st[129 + c],
          m2 = (float)st[130 + c], m3 = (float)st[131 + c];
    float a0 = (float)st[192 + c], a1 = (float)st[193 + c],
          a2 = (float)st[194 + c], a3 = (float)st[195 + c];
    float r0 = m0 * f0 + a0; r0 = r0 > 0.f ? r0 : 0.1f * r0;
    float r1 = m1 * f1 + a1; r1 = r1 > 0.f ? r1 : 0.1f * r1;
    float r2 = m2 * f2 + a2; r2 = r2 > 0.f ? r2 : 0.1f * r2;
    float r3 = m3 * f3 + a3; r3 = r3 > 0.f ? r3 : 0.1f * r3;
    float dv = dis[row];
    uint2 o;
    o.x = (u32)f2bf(r0 * dv) | ((u32)f2bf(r1 * dv) << 16);
    o.y = (u32)f2bf(r2 * dv) | ((u32)f2bf(r3 * dv) << 16);
    ((uint2*)p)[idx] = o;
}

// layer3 apply + layer4 dot fused (t bf16, stride 256)
__global__ void k_apply3_dot(const u16* __restrict__ t, const double* __restrict__ st,
                             const float* __restrict__ dis, const float* __restrict__ W4,
                             float* __restrict__ q, int n) {
    int row = blockIdx.x * 4 + (threadIdx.x >> 6);
    int lane = threadIdx.x & 63;
    if (row >= n) return;
    uint2 v = ((const uint2*)t)[(size_t)row * 64 + lane];
    float f0 = bf2f_lo(v.x), f1 = bf2f_hi(v.x), f2 = bf2f_lo(v.y), f3 = bf2f_hi(v.y);
    int c = lane * 4;
    float m0 = (float)st[512 + c], m1 = (float)st[513 + c],
          m2 = (float)st[514 + c], m3 = (float)st[515 + c];
    float a0 = (float)st[768 + c], a1 = (float)st[769 + c],
          a2 = (float)st[770 + c], a3 = (float)st[771 + c];
    float b0 = m0 * f0 + a0; b0 = b0 > 0.f ? b0 : 0.1f * b0;
    float b1 = m1 * f1 + a1; b1 = b1 > 0.f ? b1 : 0.1f * b1;
    float b2 = m2 * f2 + a2; b2 = b2 > 0.f ? b2 : 0.1f * b2;
    float b3 = m3 * f3 + a3; b3 = b3 > 0.f ? b3 : 0.1f * b3;
    float4 w = ((const float4*)W4)[lane];
    float s = b0 * w.x + b1 * w.y + b2 * w.z + b3 * w.w;
#pragma unroll
    for (int off = 32; off; off >>= 1) s += __shfl_down(s, off);
    if (lane == 0) q[row] = dis[row] * s;
}

extern "C" void kernel_launch(void* const* d_in, const int* in_sizes, int n_in,
                              void* d_out, int out_size, void* d_ws, size_t ws_size,
                              hipStream_t stream) {
    const float* x  = (const float*)d_in[0];
    const int*   ei = (const int*)d_in[1];
    const int E = in_sizes[1] / 2;
    const int* src = ei;
    const int* dst = ei + E;
    const float* W1 = (const float*)d_in[2];
    const float* g1 = (const float*)d_in[4];
    const float* be1= (const float*)d_in[5];
    const float* W2 = (const float*)d_in[6];
    const float* g2 = (const float*)d_in[8];
    const float* be2= (const float*)d_in[9];
    const float* W3 = (const float*)d_in[10];
    const float* g3 = (const float*)d_in[12];
    const float* be3= (const float*)d_in[13];
    const float* W4 = (const float*)d_in[14];
    const float* b4 = (const float*)d_in[15];
    float* out = (float*)d_out;

    // workspace layout
    u16*   T  = (u16*)d_ws;                         // N*256 bf16 (GEMM outputs)
    u16*   P  = T + (size_t)NN * 256;               // N*64  bf16 (activations)
    float* Z  = (float*)(P + (size_t)NN * 64);      // N*64  f32 (aggregated)
    float* Q  = Z + (size_t)NN * 64;                // N     f32
    float* P0 = Q + NN;                             // N*3   f32 (prescaled x)
    double* st = (double*)(P0 + NN * 3 + 4);        // 3*1024 doubles
    double *st0 = st, *st1 = st + 1024, *st2 = st + 2048;
    int* cnt      = (int*)(st + 3 * 1024);          // N
    int* rowstart = cnt + NN;                       // N+1 (+pad)
    int* adj      = rowstart + NN + 8;              // E
    float* dis    = (float*)(adj + E);              // N

    hipMemsetAsync(cnt, 0, NN * sizeof(int), stream);
    hipMemsetAsync(st, 0, 3 * 1024 * sizeof(double), stream);

    k_counti<<<(E + 255) / 256, 256, 0, stream>>>(dst, E, cnt);
    k_dis<<<(NN + 255) / 256, 256, 0, stream>>>(cnt, dis, NN);
    k_scan<<<1, 1024, 0, stream>>>(cnt, rowstart, NN, E);
    hipMemsetAsync(cnt, 0, NN * sizeof(int), stream);
    k_fill<<<(E + 255) / 256, 256, 0, stream>>>(src, dst, E, rowstart, cnt, adj);

    const int rows_grid = (NN + 255) / 256;
    const int g16_grid  = (NN + 15) / 16;
    const int wave4_grid = (NN + 3) / 4;
    const int gemm_rows = (NN + 63) / 64;
    const int app_grid = (NN * 16 + 255) / 256;

    // ---- Layer 1 ----
    k_pre3<<<(NN * 3 + 255) / 256, 256, 0, stream>>>(x, dis, P0, NN * 3);
    k_gather3<<<rows_grid, 256, 0, stream>>>(rowstart, adj, P0, dis, Z, NN);
    k_gemm3_stats<<<gemm_rows, 256, 0, stream>>>(Z, W1, T, st0, NN);
    k_bn_fin<64><<<1, 64, 0, stream>>>(st0, g1, be1, NN);
    k_apply64<<<app_grid, 256, 0, stream>>>(T, dis, st0, P, NN);

    // ---- Layer 2 ----
    k_gather64_bf16<<<g16_grid, 256, 0, stream>>>(rowstart, adj, P, dis, Z, NN);
    k_gemm64c<<<dim3(gemm_rows, 1), 256, 0, stream>>>(Z, W2, 16, T, 64, st1, 64, NN);
    k_bn_fin<64><<<1, 64, 0, stream>>>(st1, g2, be2, NN);
    k_apply64<<<app_grid, 256, 0, stream>>>(T, dis, st1, P, NN);

    // ---- Layer 3 ----
    k_gather64_bf16<<<g16_grid, 256, 0, stream>>>(rowstart, adj, P, dis, Z, NN);
    k_gemm64c<<<dim3(gemm_rows, 4), 256, 0, stream>>>(Z, W3, 64, T, 256, st2, 256, NN);
    k_bn_fin<256><<<1, 256, 0, stream>>>(st2, g3, be3, NN);

    // ---- Layer 3 apply + Layer 4 dot, then scalar gather + sigmoid ----
    k_apply3_dot<<<wave4_grid, 256, 0, stream>>>(T, st2, dis, W4, Q, NN);
    k_gather1_final<<<rows_grid, 256, 0, stream>>>(rowstart, adj, Q, dis, b4, out, NN);
}

// Round 5
// 415.248 us; speedup vs baseline: 1.6382x; 1.6382x over previous
//
#include <hip/hip_runtime.h>
#include <math.h>

#define NN 50000
#define NP 50048   // padded to 64-row multiple (782 * 64)

typedef unsigned short u16;
typedef unsigned int u32;

typedef __bf16 bf16x8 __attribute__((ext_vector_type(8)));
typedef float f32x4 __attribute__((ext_vector_type(4)));

__device__ __forceinline__ u16 f2bf(float f) {
    u32 u = __float_as_uint(f);
    u32 r = (u + 0x7FFFu + ((u >> 16) & 1u)) >> 16;
    return (u16)r;
}
__device__ __forceinline__ float bf2f_lo(u32 v) { return __uint_as_float(v << 16); }
__device__ __forceinline__ float bf2f_hi(u32 v) { return __uint_as_float(v & 0xFFFF0000u); }

// ---------------- CSR build ----------------
__global__ void k_counti(const int* __restrict__ dst, int E, int* __restrict__ cnt) {
    int i = blockIdx.x * 256 + threadIdx.x;
    if (i < E) atomicAdd(&cnt[dst[i]], 1);
}

__global__ void k_dis(const int* __restrict__ cnt, float* __restrict__ dis, int n) {
    int i = blockIdx.x * 256 + threadIdx.x;
    if (i < n) dis[i] = rsqrtf((float)cnt[i] + 1.0f);
}

__global__ void k_scan(const int* __restrict__ cnt, int* __restrict__ rowstart, int n, int E) {
    __shared__ int ssum[1024];
    int t = threadIdx.x;
    const int CH = (n + 1023) / 1024;
    int beg = t * CH, end = min(beg + CH, n);
    int s = 0;
    for (int i = beg; i < end; i++) s += cnt[i];
    ssum[t] = s; __syncthreads();
    int v = s;
    for (int off = 1; off < 1024; off <<= 1) {
        int o = (t >= off) ? ssum[t - off] : 0;
        __syncthreads();
        v += o; ssum[t] = v;
        __syncthreads();
    }
    int base = v - s;
    for (int i = beg; i < end; i++) { rowstart[i] = base; base += cnt[i]; }
    if (t == 1023) rowstart[n] = E;
}

__global__ void k_fill(const int* __restrict__ src, const int* __restrict__ dst, int E,
                       const int* __restrict__ rowstart, int* __restrict__ cur,
                       int* __restrict__ adj) {
    int e = blockIdx.x * 256 + threadIdx.x;
    if (e < E) {
        int d = dst[e];
        int p = atomicAdd(&cur[d], 1);
        adj[rowstart[d] + p] = src[e];
    }
}

// ---------------- weight prep: W[k][o] f32 -> Wt hi/lo [o][k] bf16 ----------------
__global__ void k_wprep(const float* __restrict__ W, int OUT,
                        u16* __restrict__ wth, u16* __restrict__ wtl) {
    int idx = blockIdx.x * 256 + threadIdx.x;
    if (idx >= OUT * 64) return;
    int o = idx >> 6, k = idx & 63;
    float w = W[k * OUT + o];
    u16 h = f2bf(w);
    float hf = __uint_as_float((u32)h << 16);
    u16 l = f2bf(w - hf);
    wth[(size_t)o * 64 + k] = h;
    wtl[(size_t)o * 64 + k] = l;
}

// ---------------- layer-1 front ----------------
__global__ void k_pre3(const float* __restrict__ x, const float* __restrict__ dis,
                       float* __restrict__ p, int n3) {
    int i = blockIdx.x * 256 + threadIdx.x;
    if (i < n3) p[i] = dis[i / 3] * x[i];
}

__global__ void k_gather3(const int* __restrict__ rowstart, const int* __restrict__ adj,
                          const float* __restrict__ p, const float* __restrict__ dis,
                          float* __restrict__ z, int n) {
    int row = blockIdx.x * 256 + threadIdx.x;
    if (row >= n) return;
    float a0 = p[row * 3], a1 = p[row * 3 + 1], a2 = p[row * 3 + 2];
    int beg = rowstart[row], end = rowstart[row + 1];
    for (int j = beg; j < end; j++) {
        int s = adj[j];
        a0 += p[s * 3]; a1 += p[s * 3 + 1]; a2 += p[s * 3 + 2];
    }
    float dv = dis[row];
    z[row * 3] = dv * a0; z[row * 3 + 1] = dv * a1; z[row * 3 + 2] = dv * a2;
}

// ---------------- bf16 gather (64 feats): 16 lanes/row; bf16 output ----------------
__global__ __launch_bounds__(256) void k_gather64_bf16(const int* __restrict__ rowstart,
        const int* __restrict__ adj, const u16* __restrict__ pb,
        const float* __restrict__ dis, u16* __restrict__ zb, int n) {
    int row = blockIdx.x * 16 + (threadIdx.x >> 4);
    int lane = threadIdx.x & 15;
    if (row >= n) return;
    uint2 v = *((const uint2*)(pb + ((size_t)row << 6)) + lane);
    float a0 = bf2f_lo(v.x), a1 = bf2f_hi(v.x), a2 = bf2f_lo(v.y), a3 = bf2f_hi(v.y);
    int beg = rowstart[row], end = rowstart[row + 1];
    int j = beg;
    for (; j + 3 < end; j += 4) {
        int s0 = adj[j], s1 = adj[j + 1], s2 = adj[j + 2], s3 = adj[j + 3];
        uint2 v0 = *((const uint2*)(pb + ((size_t)s0 << 6)) + lane);
        uint2 v1 = *((const uint2*)(pb + ((size_t)s1 << 6)) + lane);
        uint2 v2 = *((const uint2*)(pb + ((size_t)s2 << 6)) + lane);
        uint2 v3 = *((const uint2*)(pb + ((size_t)s3 << 6)) + lane);
        a0 += (bf2f_lo(v0.x) + bf2f_lo(v1.x)) + (bf2f_lo(v2.x) + bf2f_lo(v3.x));
        a1 += (bf2f_hi(v0.x) + bf2f_hi(v1.x)) + (bf2f_hi(v2.x) + bf2f_hi(v3.x));
        a2 += (bf2f_lo(v0.y) + bf2f_lo(v1.y)) + (bf2f_lo(v2.y) + bf2f_lo(v3.y));
        a3 += (bf2f_hi(v0.y) + bf2f_hi(v1.y)) + (bf2f_hi(v2.y) + bf2f_hi(v3.y));
    }
    for (; j < end; j++) {
        uint2 v0 = *((const uint2*)(pb + ((size_t)adj[j] << 6)) + lane);
        a0 += bf2f_lo(v0.x); a1 += bf2f_hi(v0.x);
        a2 += bf2f_lo(v0.y); a3 += bf2f_hi(v0.y);
    }
    float dv = dis[row];
    uint2 o;
    o.x = (u32)f2bf(a0 * dv) | ((u32)f2bf(a1 * dv) << 16);
    o.y = (u32)f2bf(a2 * dv) | ((u32)f2bf(a3 * dv) << 16);
    ((uint2*)(zb + ((size_t)row << 6)))[lane] = o;
}

__global__ void k_gather1_final(const int* __restrict__ rowstart, const int* __restrict__ adj,
                                const float* __restrict__ q, const float* __restrict__ dis,
                                const float* __restrict__ b4, float* __restrict__ out, int n) {
    int row = blockIdx.x * 256 + threadIdx.x;
    if (row >= n) return;
    float acc = q[row];
    int beg = rowstart[row], end = rowstart[row + 1];
    for (int j = beg; j < end; j++) acc += q[adj[j]];
    float v = dis[row] * acc + b4[0];
    out[row] = 1.f / (1.f + expf(-v));
}

// ---------------- MFMA GEMM: [NP x 64] bf16 @ [64 x OUT] (hi/lo bf16) + stats ----------------
// grid (NP/64, OUT/64), 256 thr = 4 waves; wave: 64 rows x 16 cols.
__global__ __launch_bounds__(256) void k_mgemm(const u16* __restrict__ zb,
        const u16* __restrict__ wth, const u16* __restrict__ wtl,
        u16* __restrict__ t, int tstride, double* __restrict__ st, int F) {
    const int wv = threadIdx.x >> 6, lane = threadIdx.x & 63;
    const int lc = lane & 15, lk = lane >> 4;
    const int r0 = blockIdx.x * 64;
    const int col = blockIdx.y * 64 + wv * 16 + lc;

    const bf16x8* wh = (const bf16x8*)(wth + (size_t)col * 64 + lk * 8);
    const bf16x8* wl = (const bf16x8*)(wtl + (size_t)col * 64 + lk * 8);
    bf16x8 bh0 = wh[0], bh1 = wh[4];   // k-halves 0..31 / 32..63
    bf16x8 bl0 = wl[0], bl1 = wl[4];

    f32x4 acc[4] = {};
#pragma unroll
    for (int rt = 0; rt < 4; rt++) {
        const bf16x8* ap = (const bf16x8*)(zb + (size_t)(r0 + rt * 16 + lc) * 64 + lk * 8);
        bf16x8 a0 = ap[0], a1 = ap[4];
        acc[rt] = __builtin_amdgcn_mfma_f32_16x16x32_bf16(a0, bh0, acc[rt], 0, 0, 0);
        acc[rt] = __builtin_amdgcn_mfma_f32_16x16x32_bf16(a1, bh1, acc[rt], 0, 0, 0);
        acc[rt] = __builtin_amdgcn_mfma_f32_16x16x32_bf16(a0, bl0, acc[rt], 0, 0, 0);
        acc[rt] = __builtin_amdgcn_mfma_f32_16x16x32_bf16(a1, bl1, acc[rt], 0, 0, 0);
    }
    // store (C/D: col=lane&15, row=(lane>>4)*4+reg  [m89])
#pragma unroll
    for (int rt = 0; rt < 4; rt++) {
        int rowb = r0 + rt * 16 + lk * 4;
#pragma unroll
        for (int rg = 0; rg < 4; rg++)
            t[(size_t)(rowb + rg) * tstride + col] = f2bf(acc[rt][rg]);
    }
    // fused BN stats (pad rows are zero -> contribute nothing)
    float s = 0.f, q = 0.f;
#pragma unroll
    for (int rt = 0; rt < 4; rt++)
#pragma unroll
        for (int rg = 0; rg < 4; rg++) { float v = acc[rt][rg]; s += v; q += v * v; }
    s += __shfl_xor(s, 16); q += __shfl_xor(q, 16);
    s += __shfl_xor(s, 32); q += __shfl_xor(q, 32);
    if (lane < 16) {
        atomicAdd(&st[col], (double)s);
        atomicAdd(&st[F + col], (double)q);
    }
}

// GEMM IN=3 -> OUT=64 with fused stats, bf16 out
__global__ __launch_bounds__(256) void k_gemm3_stats(const float* __restrict__ z,
        const float* __restrict__ W, u16* __restrict__ t,
        double* __restrict__ st, int n) {
    __shared__ float sH[64 * 4];
    __shared__ float sW[3 * 64];
    __shared__ double red[2 * 16 * 64];
    const int tid = threadIdx.x;
    const int r0 = blockIdx.x * 64;
    for (int i = tid; i < 192; i += 256) {
        int r = i / 3, c = i - r * 3;
        sH[r * 4 + c] = (r0 + r < n) ? z[(size_t)(r0 + r) * 3 + c] : 0.f;
    }
    if (tid < 48) ((float4*)sW)[tid] = ((const float4*)W)[tid];
    __syncthreads();
    const int tx = tid & 15, ty = tid >> 4;
    float4 acc[4];
#pragma unroll
    for (int r = 0; r < 4; r++) acc[r] = make_float4(0.f, 0.f, 0.f, 0.f);
    const float4* sW4 = (const float4*)sW;
#pragma unroll
    for (int k = 0; k < 3; k++) {
        float4 wv = sW4[k * 16 + tx];
#pragma unroll
        for (int r = 0; r < 4; r++) {
            float hs = sH[(ty * 4 + r) * 4 + k];
            acc[r].x += hs * wv.x; acc[r].y += hs * wv.y;
            acc[r].z += hs * wv.z; acc[r].w += hs * wv.w;
        }
    }
#pragma unroll
    for (int r = 0; r < 4; r++) {
        int row = r0 + ty * 4 + r;
        if (row < n) {
            uint2 o;
            o.x = (u32)f2bf(acc[r].x) | ((u32)f2bf(acc[r].y) << 16);
            o.y = (u32)f2bf(acc[r].z) | ((u32)f2bf(acc[r].w) << 16);
            *(uint2*)&t[(size_t)row * 64 + tx * 4] = o;
        }
    }
    double* redS = red;
    double* redQ = red + 16 * 64;
    double s0 = 0, s1 = 0, s2 = 0, s3 = 0, q0 = 0, q1 = 0, q2 = 0, q3 = 0;
#pragma unroll
    for (int r = 0; r < 4; r++) {
        s0 += acc[r].x; q0 += (double)acc[r].x * acc[r].x;
        s1 += acc[r].y; q1 += (double)acc[r].y * acc[r].y;
        s2 += acc[r].z; q2 += (double)acc[r].z * acc[r].z;
        s3 += acc[r].w; q3 += (double)acc[r].w * acc[r].w;
    }
    int base = ty * 64 + tx * 4;
    redS[base + 0] = s0; redS[base + 1] = s1; redS[base + 2] = s2; redS[base + 3] = s3;
    redQ[base + 0] = q0; redQ[base + 1] = q1; redQ[base + 2] = q2; redQ[base + 3] = q3;
    __syncthreads();
    if (ty == 0) {
#pragma unroll
        for (int jj = 0; jj < 4; jj++) {
            int c = tx * 4 + jj;
            double S = 0, Q = 0;
            for (int g = 0; g < 16; g++) { S += redS[g * 64 + c]; Q += redQ[g * 64 + c]; }
            atomicAdd(&st[c], S);
            atomicAdd(&st[64 + c], Q);
        }
    }
}

template<int F>
__global__ void k_bn_fin(double* __restrict__ stats, const float* __restrict__ g,
                         const float* __restrict__ be, int n) {
    int f = threadIdx.x;
    if (f >= F) return;
    double mean = stats[f] / n;
    double var = stats[F + f] / n - mean * mean;
    if (var < 0.0) var = 0.0;
    double mult = (double)g[f] / sqrt(var + 1e-5);
    stats[2 * F + f] = mult;
    stats[3 * F + f] = (double)be[f] - mult * mean;
}

// p_bf16 = dis[v] * lrelu(mult*t_bf16 + add)   (F=64)
__global__ void k_apply64(const u16* __restrict__ t, const float* __restrict__ dis,
                          const double* __restrict__ st, u16* __restrict__ p, int n) {
    int idx = blockIdx.x * 256 + threadIdx.x;   // quad index
    if (idx >= n * 16) return;
    int row = idx >> 4, c = (idx & 15) * 4;
    uint2 v = ((const uint2*)t)[idx];
    float f0 = bf2f_lo(v.x), f1 = bf2f_hi(v.x), f2 = bf2f_lo(v.y), f3 = bf2f_hi(v.y);
    float m0 = (float)st[128 + c], m1 = (float)st[129 + c],
          m2 = (float)st[130 + c], m3 = (float)st[131 + c];
    float a0 = (float)st[192 + c], a1 = (float)st[193 + c],
          a2 = (float)st[194 + c], a3 = (float)st[195 + c];
    float r0 = m0 * f0 + a0; r0 = r0 > 0.f ? r0 : 0.1f * r0;
    float r1 = m1 * f1 + a1; r1 = r1 > 0.f ? r1 : 0.1f * r1;
    float r2 = m2 * f2 + a2; r2 = r2 > 0.f ? r2 : 0.1f * r2;
    float r3 = m3 * f3 + a3; r3 = r3 > 0.f ? r3 : 0.1f * r3;
    float dv = dis[row];
    uint2 o;
    o.x = (u32)f2bf(r0 * dv) | ((u32)f2bf(r1 * dv) << 16);
    o.y = (u32)f2bf(r2 * dv) | ((u32)f2bf(r3 * dv) << 16);
    ((uint2*)p)[idx] = o;
}

// layer3 apply + layer4 dot fused (t bf16, stride 256)
__global__ void k_apply3_dot(const u16* __restrict__ t, const double* __restrict__ st,
                             const float* __restrict__ dis, const float* __restrict__ W4,
                             float* __restrict__ q, int n) {
    int row = blockIdx.x * 4 + (threadIdx.x >> 6);
    int lane = threadIdx.x & 63;
    if (row >= n) return;
    uint2 v = ((const uint2*)t)[(size_t)row * 64 + lane];
    float f0 = bf2f_lo(v.x), f1 = bf2f_hi(v.x), f2 = bf2f_lo(v.y), f3 = bf2f_hi(v.y);
    int c = lane * 4;
    float m0 = (float)st[512 + c], m1 = (float)st[513 + c],
          m2 = (float)st[514 + c], m3 = (float)st[515 + c];
    float a0 = (float)st[768 + c], a1 = (float)st[769 + c],
          a2 = (float)st[770 + c], a3 = (float)st[771 + c];
    float b0 = m0 * f0 + a0; b0 = b0 > 0.f ? b0 : 0.1f * b0;
    float b1 = m1 * f1 + a1; b1 = b1 > 0.f ? b1 : 0.1f * b1;
    float b2 = m2 * f2 + a2; b2 = b2 > 0.f ? b2 : 0.1f * b2;
    float b3 = m3 * f3 + a3; b3 = b3 > 0.f ? b3 : 0.1f * b3;
    float4 w = ((const float4*)W4)[lane];
    float s = b0 * w.x + b1 * w.y + b2 * w.z + b3 * w.w;
#pragma unroll
    for (int off = 32; off; off >>= 1) s += __shfl_down(s, off);
    if (lane == 0) q[row] = dis[row] * s;
}

extern "C" void kernel_launch(void* const* d_in, const int* in_sizes, int n_in,
                              void* d_out, int out_size, void* d_ws, size_t ws_size,
                              hipStream_t stream) {
    const float* x  = (const float*)d_in[0];
    const int*   ei = (const int*)d_in[1];
    const int E = in_sizes[1] / 2;
    const int* src = ei;
    const int* dst = ei + E;
    const float* W1 = (const float*)d_in[2];
    const float* g1 = (const float*)d_in[4];
    const float* be1= (const float*)d_in[5];
    const float* W2 = (const float*)d_in[6];
    const float* g2 = (const float*)d_in[8];
    const float* be2= (const float*)d_in[9];
    const float* W3 = (const float*)d_in[10];
    const float* g3 = (const float*)d_in[12];
    const float* be3= (const float*)d_in[13];
    const float* W4 = (const float*)d_in[14];
    const float* b4 = (const float*)d_in[15];
    float* out = (float*)d_out;

    // workspace layout (u16 blocks first, all 16B-aligned sizes)
    u16*   T    = (u16*)d_ws;                       // NP*256 bf16
    u16*   P    = T + (size_t)NP * 256;             // NN*64  bf16
    u16*   Zb   = P + (size_t)NN * 64;              // NP*64  bf16 (pad rows zeroed)
    u16*   Wt2h = Zb + (size_t)NP * 64;             // 64*64
    u16*   Wt2l = Wt2h + 64 * 64;                   // 64*64
    u16*   Wt3h = Wt2l + 64 * 64;                   // 256*64
    u16*   Wt3l = Wt3h + 256 * 64;                  // 256*64
    double* st  = (double*)(Wt3l + 256 * 64);       // 3*1024 doubles
    double *st0 = st, *st1 = st + 1024, *st2 = st + 2048;
    float* Z3   = (float*)(st + 3 * 1024);          // NN*3
    float* P0   = Z3 + NN * 3;                      // NN*3
    float* Q    = P0 + NN * 3;                      // NN
    float* dis  = Q + NN;                           // NN
    int* cnt      = (int*)(dis + NN);               // NN
    int* rowstart = cnt + NN;                       // NN+1 (+pad)
    int* adj      = rowstart + NN + 8;              // E

    hipMemsetAsync(cnt, 0, NN * sizeof(int), stream);
    hipMemsetAsync(st, 0, 3 * 1024 * sizeof(double), stream);
    hipMemsetAsync(Zb + (size_t)NN * 64, 0, (size_t)(NP - NN) * 64 * sizeof(u16), stream);

    k_counti<<<(E + 255) / 256, 256, 0, stream>>>(dst, E, cnt);
    k_dis<<<(NN + 255) / 256, 256, 0, stream>>>(cnt, dis, NN);
    k_scan<<<1, 1024, 0, stream>>>(cnt, rowstart, NN, E);
    hipMemsetAsync(cnt, 0, NN * sizeof(int), stream);
    k_fill<<<(E + 255) / 256, 256, 0, stream>>>(src, dst, E, rowstart, cnt, adj);

    k_wprep<<<(64 * 64 + 255) / 256, 256, 0, stream>>>(W2, 64, Wt2h, Wt2l);
    k_wprep<<<(256 * 64 + 255) / 256, 256, 0, stream>>>(W3, 256, Wt3h, Wt3l);

    const int rows_grid = (NN + 255) / 256;
    const int g16_grid  = (NN + 15) / 16;
    const int wave4_grid = (NN + 3) / 4;
    const int gemm_rows = NP / 64;                 // 782
    const int app_grid = (NN * 16 + 255) / 256;

    // ---- Layer 1 ----
    k_pre3<<<(NN * 3 + 255) / 256, 256, 0, stream>>>(x, dis, P0, NN * 3);
    k_gather3<<<rows_grid, 256, 0, stream>>>(rowstart, adj, P0, dis, Z3, NN);
    k_gemm3_stats<<<gemm_rows, 256, 0, stream>>>(Z3, W1, T, st0, NN);
    k_bn_fin<64><<<1, 64, 0, stream>>>(st0, g1, be1, NN);
    k_apply64<<<app_grid, 256, 0, stream>>>(T, dis, st0, P, NN);

    // ---- Layer 2 ----
    k_gather64_bf16<<<g16_grid, 256, 0, stream>>>(rowstart, adj, P, dis, Zb, NN);
    k_mgemm<<<dim3(gemm_rows, 1), 256, 0, stream>>>(Zb, Wt2h, Wt2l, T, 64, st1, 64);
    k_bn_fin<64><<<1, 64, 0, stream>>>(st1, g2, be2, NN);
    k_apply64<<<app_grid, 256, 0, stream>>>(T, dis, st1, P, NN);

    // ---- Layer 3 ----
    k_gather64_bf16<<<g16_grid, 256, 0, stream>>>(rowstart, adj, P, dis, Zb, NN);
    k_mgemm<<<dim3(gemm_rows, 4), 256, 0, stream>>>(Zb, Wt3h, Wt3l, T, 256, st2, 256);
    k_bn_fin<256><<<1, 256, 0, stream>>>(st2, g3, be3, NN);

    // ---- Layer 3 apply + Layer 4 dot, then scalar gather + sigmoid ----
    k_apply3_dot<<<wave4_grid, 256, 0, stream>>>(T, st2, dis, W4, Q, NN);
    k_gather1_final<<<rows_grid, 256, 0, stream>>>(rowstart, adj, Q, dis, b4, out, NN);
}

// Round 6
// 347.455 us; speedup vs baseline: 1.9578x; 1.1951x over previous
//
#include <hip/hip_runtime.h>
#include <math.h>

#define NN 50000
#define NP 50048   // padded to 64-row multiple (782 * 64)
#define SCAN_NB ((NN + 255) / 256)   // 196

typedef unsigned short u16;
typedef unsigned int u32;

typedef __bf16 bf16x8 __attribute__((ext_vector_type(8)));
typedef float f32x4 __attribute__((ext_vector_type(4)));

__device__ __forceinline__ u16 f2bf(float f) {
    u32 u = __float_as_uint(f);
    u32 r = (u + 0x7FFFu + ((u >> 16) & 1u)) >> 16;
    return (u16)r;
}
__device__ __forceinline__ float bf2f_lo(u32 v) { return __uint_as_float(v << 16); }
__device__ __forceinline__ float bf2f_hi(u32 v) { return __uint_as_float(v & 0xFFFF0000u); }

// ---------------- CSR build ----------------
__global__ void k_counti(const int* __restrict__ dst, int E, int* __restrict__ cnt) {
    int i = blockIdx.x * 256 + threadIdx.x;
    if (i < E) atomicAdd(&cnt[dst[i]], 1);
}

__global__ void k_dis(const int* __restrict__ cnt, float* __restrict__ dis, int n) {
    int i = blockIdx.x * 256 + threadIdx.x;
    if (i < n) dis[i] = rsqrtf((float)cnt[i] + 1.0f);
}

// phase 1: per-block sums of 256 counts
__global__ void k_bsum(const int* __restrict__ cnt, int* __restrict__ bsum, int n) {
    __shared__ int sh[256];
    int i = blockIdx.x * 256 + threadIdx.x;
    sh[threadIdx.x] = (i < n) ? cnt[i] : 0;
    __syncthreads();
    for (int off = 128; off; off >>= 1) {
        if (threadIdx.x < off) sh[threadIdx.x] += sh[threadIdx.x + off];
        __syncthreads();
    }
    if (threadIdx.x == 0) bsum[blockIdx.x] = sh[0];
}

// phase 2: exclusive scan of block sums (nb <= 256), single block
__global__ void k_scan_bsum(int* __restrict__ bsum, int nb) {
    __shared__ int sh[256];
    int t = threadIdx.x;
    int v0 = (t < nb) ? bsum[t] : 0;
    sh[t] = v0; __syncthreads();
    int inc = v0;
    for (int off = 1; off < 256; off <<= 1) {
        int o = (t >= off) ? sh[t - off] : 0;
        __syncthreads();
        inc += o; sh[t] = inc;
        __syncthreads();
    }
    if (t < nb) bsum[t] = inc - v0;   // exclusive prefix
}

// phase 3: intra-block scan + block prefix -> rowstart
__global__ void k_scan_fin(const int* __restrict__ cnt, const int* __restrict__ bpre,
                           int* __restrict__ rowstart, int n, int E) {
    __shared__ int sh[256];
    int b = blockIdx.x, t = threadIdx.x;
    int i = b * 256 + t;
    int v0 = (i < n) ? cnt[i] : 0;
    sh[t] = v0; __syncthreads();
    int inc = v0;
    for (int off = 1; off < 256; off <<= 1) {
        int o = (t >= off) ? sh[t - off] : 0;
        __syncthreads();
        inc += o; sh[t] = inc;
        __syncthreads();
    }
    if (i < n) rowstart[i] = bpre[b] + inc - v0;
    if (b == gridDim.x - 1 && t == 0) rowstart[n] = E;
}

__global__ void k_fill(const int* __restrict__ src, const int* __restrict__ dst, int E,
                       const int* __restrict__ rowstart, int* __restrict__ cur,
                       int* __restrict__ adj) {
    int e = blockIdx.x * 256 + threadIdx.x;
    if (e < E) {
        int d = dst[e];
        int p = atomicAdd(&cur[d], 1);
        adj[rowstart[d] + p] = src[e];
    }
}

// ---------------- weight prep: W[k][o] f32 -> Wt hi/lo [o][k] bf16 ----------------
__global__ void k_wprep(const float* __restrict__ W, int OUT,
                        u16* __restrict__ wth, u16* __restrict__ wtl) {
    int idx = blockIdx.x * 256 + threadIdx.x;
    if (idx >= OUT * 64) return;
    int o = idx >> 6, k = idx & 63;
    float w = W[k * OUT + o];
    u16 h = f2bf(w);
    float hf = __uint_as_float((u32)h << 16);
    u16 l = f2bf(w - hf);
    wth[(size_t)o * 64 + k] = h;
    wtl[(size_t)o * 64 + k] = l;
}

// ---------------- layer-1 front ----------------
__global__ void k_pre3(const float* __restrict__ x, const float* __restrict__ dis,
                       float* __restrict__ p, int n3) {
    int i = blockIdx.x * 256 + threadIdx.x;
    if (i < n3) p[i] = dis[i / 3] * x[i];
}

__global__ void k_gather3(const int* __restrict__ rowstart, const int* __restrict__ adj,
                          const float* __restrict__ p, const float* __restrict__ dis,
                          float* __restrict__ z, int n) {
    int row = blockIdx.x * 256 + threadIdx.x;
    if (row >= n) return;
    float a0 = p[row * 3], a1 = p[row * 3 + 1], a2 = p[row * 3 + 2];
    int beg = rowstart[row], end = rowstart[row + 1];
    for (int j = beg; j < end; j++) {
        int s = adj[j];
        a0 += p[s * 3]; a1 += p[s * 3 + 1]; a2 += p[s * 3 + 2];
    }
    float dv = dis[row];
    z[row * 3] = dv * a0; z[row * 3 + 1] = dv * a1; z[row * 3 + 2] = dv * a2;
}

// ---------------- bf16 gather (64 feats): 16 lanes/row; bf16 output ----------------
__global__ __launch_bounds__(256) void k_gather64_bf16(const int* __restrict__ rowstart,
        const int* __restrict__ adj, const u16* __restrict__ pb,
        const float* __restrict__ dis, u16* __restrict__ zb, int n) {
    int row = blockIdx.x * 16 + (threadIdx.x >> 4);
    int lane = threadIdx.x & 15;
    if (row >= n) return;
    uint2 v = *((const uint2*)(pb + ((size_t)row << 6)) + lane);
    float a0 = bf2f_lo(v.x), a1 = bf2f_hi(v.x), a2 = bf2f_lo(v.y), a3 = bf2f_hi(v.y);
    int beg = rowstart[row], end = rowstart[row + 1];
    int j = beg;
    for (; j + 3 < end; j += 4) {
        int s0 = adj[j], s1 = adj[j + 1], s2 = adj[j + 2], s3 = adj[j + 3];
        uint2 v0 = *((const uint2*)(pb + ((size_t)s0 << 6)) + lane);
        uint2 v1 = *((const uint2*)(pb + ((size_t)s1 << 6)) + lane);
        uint2 v2 = *((const uint2*)(pb + ((size_t)s2 << 6)) + lane);
        uint2 v3 = *((const uint2*)(pb + ((size_t)s3 << 6)) + lane);
        a0 += (bf2f_lo(v0.x) + bf2f_lo(v1.x)) + (bf2f_lo(v2.x) + bf2f_lo(v3.x));
        a1 += (bf2f_hi(v0.x) + bf2f_hi(v1.x)) + (bf2f_hi(v2.x) + bf2f_hi(v3.x));
        a2 += (bf2f_lo(v0.y) + bf2f_lo(v1.y)) + (bf2f_lo(v2.y) + bf2f_lo(v3.y));
        a3 += (bf2f_hi(v0.y) + bf2f_hi(v1.y)) + (bf2f_hi(v2.y) + bf2f_hi(v3.y));
    }
    for (; j < end; j++) {
        uint2 v0 = *((const uint2*)(pb + ((size_t)adj[j] << 6)) + lane);
        a0 += bf2f_lo(v0.x); a1 += bf2f_hi(v0.x);
        a2 += bf2f_lo(v0.y); a3 += bf2f_hi(v0.y);
    }
    float dv = dis[row];
    uint2 o;
    o.x = (u32)f2bf(a0 * dv) | ((u32)f2bf(a1 * dv) << 16);
    o.y = (u32)f2bf(a2 * dv) | ((u32)f2bf(a3 * dv) << 16);
    ((uint2*)(zb + ((size_t)row << 6)))[lane] = o;
}

__global__ void k_gather1_final(const int* __restrict__ rowstart, const int* __restrict__ adj,
                                const float* __restrict__ q, const float* __restrict__ dis,
                                const float* __restrict__ b4, float* __restrict__ out, int n) {
    int row = blockIdx.x * 256 + threadIdx.x;
    if (row >= n) return;
    float acc = q[row];
    int beg = rowstart[row], end = rowstart[row + 1];
    for (int j = beg; j < end; j++) acc += q[adj[j]];
    float v = dis[row] * acc + b4[0];
    out[row] = 1.f / (1.f + expf(-v));
}

// ---------------- MFMA GEMM: [NP x 64] bf16 @ [64 x OUT] (hi/lo bf16) + stats ----------------
__global__ __launch_bounds__(256) void k_mgemm(const u16* __restrict__ zb,
        const u16* __restrict__ wth, const u16* __restrict__ wtl,
        u16* __restrict__ t, int tstride, double* __restrict__ st, int F) {
    const int wv = threadIdx.x >> 6, lane = threadIdx.x & 63;
    const int lc = lane & 15, lk = lane >> 4;
    const int r0 = blockIdx.x * 64;
    const int col = blockIdx.y * 64 + wv * 16 + lc;

    const bf16x8* wh = (const bf16x8*)(wth + (size_t)col * 64 + lk * 8);
    const bf16x8* wl = (const bf16x8*)(wtl + (size_t)col * 64 + lk * 8);
    bf16x8 bh0 = wh[0], bh1 = wh[4];
    bf16x8 bl0 = wl[0], bl1 = wl[4];

    f32x4 acc[4] = {};
#pragma unroll
    for (int rt = 0; rt < 4; rt++) {
        const bf16x8* ap = (const bf16x8*)(zb + (size_t)(r0 + rt * 16 + lc) * 64 + lk * 8);
        bf16x8 a0 = ap[0], a1 = ap[4];
        acc[rt] = __builtin_amdgcn_mfma_f32_16x16x32_bf16(a0, bh0, acc[rt], 0, 0, 0);
        acc[rt] = __builtin_amdgcn_mfma_f32_16x16x32_bf16(a1, bh1, acc[rt], 0, 0, 0);
        acc[rt] = __builtin_amdgcn_mfma_f32_16x16x32_bf16(a0, bl0, acc[rt], 0, 0, 0);
        acc[rt] = __builtin_amdgcn_mfma_f32_16x16x32_bf16(a1, bl1, acc[rt], 0, 0, 0);
    }
#pragma unroll
    for (int rt = 0; rt < 4; rt++) {
        int rowb = r0 + rt * 16 + lk * 4;
#pragma unroll
        for (int rg = 0; rg < 4; rg++)
            t[(size_t)(rowb + rg) * tstride + col] = f2bf(acc[rt][rg]);
    }
    float s = 0.f, q = 0.f;
#pragma unroll
    for (int rt = 0; rt < 4; rt++)
#pragma unroll
        for (int rg = 0; rg < 4; rg++) { float v = acc[rt][rg]; s += v; q += v * v; }
    s += __shfl_xor(s, 16); q += __shfl_xor(q, 16);
    s += __shfl_xor(s, 32); q += __shfl_xor(q, 32);
    if (lane < 16) {
        atomicAdd(&st[col], (double)s);
        atomicAdd(&st[F + col], (double)q);
    }
}

// GEMM IN=3 -> OUT=64 with fused stats, bf16 out
__global__ __launch_bounds__(256) void k_gemm3_stats(const float* __restrict__ z,
        const float* __restrict__ W, u16* __restrict__ t,
        double* __restrict__ st, int n) {
    __shared__ float sH[64 * 4];
    __shared__ float sW[3 * 64];
    __shared__ double red[2 * 16 * 64];
    const int tid = threadIdx.x;
    const int r0 = blockIdx.x * 64;
    for (int i = tid; i < 192; i += 256) {
        int r = i / 3, c = i - r * 3;
        sH[r * 4 + c] = (r0 + r < n) ? z[(size_t)(r0 + r) * 3 + c] : 0.f;
    }
    if (tid < 48) ((float4*)sW)[tid] = ((const float4*)W)[tid];
    __syncthreads();
    const int tx = tid & 15, ty = tid >> 4;
    float4 acc[4];
#pragma unroll
    for (int r = 0; r < 4; r++) acc[r] = make_float4(0.f, 0.f, 0.f, 0.f);
    const float4* sW4 = (const float4*)sW;
#pragma unroll
    for (int k = 0; k < 3; k++) {
        float4 wv = sW4[k * 16 + tx];
#pragma unroll
        for (int r = 0; r < 4; r++) {
            float hs = sH[(ty * 4 + r) * 4 + k];
            acc[r].x += hs * wv.x; acc[r].y += hs * wv.y;
            acc[r].z += hs * wv.z; acc[r].w += hs * wv.w;
        }
    }
#pragma unroll
    for (int r = 0; r < 4; r++) {
        int row = r0 + ty * 4 + r;
        if (row < n) {
            uint2 o;
            o.x = (u32)f2bf(acc[r].x) | ((u32)f2bf(acc[r].y) << 16);
            o.y = (u32)f2bf(acc[r].z) | ((u32)f2bf(acc[r].w) << 16);
            *(uint2*)&t[(size_t)row * 64 + tx * 4] = o;
        }
    }
    double* redS = red;
    double* redQ = red + 16 * 64;
    double s0 = 0, s1 = 0, s2 = 0, s3 = 0, q0 = 0, q1 = 0, q2 = 0, q3 = 0;
#pragma unroll
    for (int r = 0; r < 4; r++) {
        s0 += acc[r].x; q0 += (double)acc[r].x * acc[r].x;
        s1 += acc[r].y; q1 += (double)acc[r].y * acc[r].y;
        s2 += acc[r].z; q2 += (double)acc[r].z * acc[r].z;
        s3 += acc[r].w; q3 += (double)acc[r].w * acc[r].w;
    }
    int base = ty * 64 + tx * 4;
    redS[base + 0] = s0; redS[base + 1] = s1; redS[base + 2] = s2; redS[base + 3] = s3;
    redQ[base + 0] = q0; redQ[base + 1] = q1; redQ[base + 2] = q2; redQ[base + 3] = q3;
    __syncthreads();
    if (ty == 0) {
#pragma unroll
        for (int jj = 0; jj < 4; jj++) {
            int c = tx * 4 + jj;
            double S = 0, Q = 0;
            for (int g = 0; g < 16; g++) { S += redS[g * 64 + c]; Q += redQ[g * 64 + c]; }
            atomicAdd(&st[c], S);
            atomicAdd(&st[64 + c], Q);
        }
    }
}

template<int F>
__global__ void k_bn_fin(double* __restrict__ stats, const float* __restrict__ g,
                         const float* __restrict__ be, int n) {
    int f = threadIdx.x;
    if (f >= F) return;
    double mean = stats[f] / n;
    double var = stats[F + f] / n - mean * mean;
    if (var < 0.0) var = 0.0;
    double mult = (double)g[f] / sqrt(var + 1e-5);
    stats[2 * F + f] = mult;
    stats[3 * F + f] = (double)be[f] - mult * mean;
}

// p_bf16 = dis[v] * lrelu(mult*t_bf16 + add)   (F=64)
__global__ void k_apply64(const u16* __restrict__ t, const float* __restrict__ dis,
                          const double* __restrict__ st, u16* __restrict__ p, int n) {
    int idx = blockIdx.x * 256 + threadIdx.x;
    if (idx >= n * 16) return;
    int row = idx >> 4, c = (idx & 15) * 4;
    uint2 v = ((const uint2*)t)[idx];
    float f0 = bf2f_lo(v.x), f1 = bf2f_hi(v.x), f2 = bf2f_lo(v.y), f3 = bf2f_hi(v.y);
    float m0 = (float)st[128 + c], m1 = (float)st[129 + c],
          m2 = (float)st[130 + c], m3 = (float)st[131 + c];
    float a0 = (float)st[192 + c], a1 = (float)st[193 + c],
          a2 = (float)st[194 + c], a3 = (float)st[195 + c];
    float r0 = m0 * f0 + a0; r0 = r0 > 0.f ? r0 : 0.1f * r0;
    float r1 = m1 * f1 + a1; r1 = r1 > 0.f ? r1 : 0.1f * r1;
    float r2 = m2 * f2 + a2; r2 = r2 > 0.f ? r2 : 0.1f * r2;
    float r3 = m3 * f3 + a3; r3 = r3 > 0.f ? r3 : 0.1f * r3;
    float dv = dis[row];
    uint2 o;
    o.x = (u32)f2bf(r0 * dv) | ((u32)f2bf(r1 * dv) << 16);
    o.y = (u32)f2bf(r2 * dv) | ((u32)f2bf(r3 * dv) << 16);
    ((uint2*)p)[idx] = o;
}

// layer3 apply + layer4 dot fused (t bf16, stride 256)
__global__ void k_apply3_dot(const u16* __restrict__ t, const double* __restrict__ st,
                             const float* __restrict__ dis, const float* __restrict__ W4,
                             float* __restrict__ q, int n) {
    int row = blockIdx.x * 4 + (threadIdx.x >> 6);
    int lane = threadIdx.x & 63;
    if (row >= n) return;
    uint2 v = ((const uint2*)t)[(size_t)row * 64 + lane];
    float f0 = bf2f_lo(v.x), f1 = bf2f_hi(v.x), f2 = bf2f_lo(v.y), f3 = bf2f_hi(v.y);
    int c = lane * 4;
    float m0 = (float)st[512 + c], m1 = (float)st[513 + c],
          m2 = (float)st[514 + c], m3 = (float)st[515 + c];
    float a0 = (float)st[768 + c], a1 = (float)st[769 + c],
          a2 = (float)st[770 + c], a3 = (float)st[771 + c];
    float b0 = m0 * f0 + a0; b0 = b0 > 0.f ? b0 : 0.1f * b0;
    float b1 = m1 * f1 + a1; b1 = b1 > 0.f ? b1 : 0.1f * b1;
    float b2 = m2 * f2 + a2; b2 = b2 > 0.f ? b2 : 0.1f * b2;
    float b3 = m3 * f3 + a3; b3 = b3 > 0.f ? b3 : 0.1f * b3;
    float4 w = ((const float4*)W4)[lane];
    float s = b0 * w.x + b1 * w.y + b2 * w.z + b3 * w.w;
#pragma unroll
    for (int off = 32; off; off >>= 1) s += __shfl_down(s, off);
    if (lane == 0) q[row] = dis[row] * s;
}

extern "C" void kernel_launch(void* const* d_in, const int* in_sizes, int n_in,
                              void* d_out, int out_size, void* d_ws, size_t ws_size,
                              hipStream_t stream) {
    const float* x  = (const float*)d_in[0];
    const int*   ei = (const int*)d_in[1];
    const int E = in_sizes[1] / 2;
    const int* src = ei;
    const int* dst = ei + E;
    const float* W1 = (const float*)d_in[2];
    const float* g1 = (const float*)d_in[4];
    const float* be1= (const float*)d_in[5];
    const float* W2 = (const float*)d_in[6];
    const float* g2 = (const float*)d_in[8];
    const float* be2= (const float*)d_in[9];
    const float* W3 = (const float*)d_in[10];
    const float* g3 = (const float*)d_in[12];
    const float* be3= (const float*)d_in[13];
    const float* W4 = (const float*)d_in[14];
    const float* b4 = (const float*)d_in[15];
    float* out = (float*)d_out;

    // workspace layout
    u16*   T    = (u16*)d_ws;                       // NP*256 bf16
    u16*   P    = T + (size_t)NP * 256;             // NN*64  bf16
    u16*   Zb   = P + (size_t)NN * 64;              // NP*64  bf16 (pad rows zeroed)
    u16*   Wt2h = Zb + (size_t)NP * 64;             // 64*64
    u16*   Wt2l = Wt2h + 64 * 64;                   // 64*64
    u16*   Wt3h = Wt2l + 64 * 64;                   // 256*64
    u16*   Wt3l = Wt3h + 256 * 64;                  // 256*64
    double* st  = (double*)(Wt3l + 256 * 64);       // 3*1024 doubles
    double *st0 = st, *st1 = st + 1024, *st2 = st + 2048;
    float* Z3   = (float*)(st + 3 * 1024);          // NN*3
    float* P0   = Z3 + NN * 3;                      // NN*3
    float* Q    = P0 + NN * 3;                      // NN
    float* dis  = Q + NN;                           // NN
    int* cnt      = (int*)(dis + NN);               // NN
    int* rowstart = cnt + NN;                       // NN+1 (+pad)
    int* adj      = rowstart + NN + 8;              // E
    int* bsum     = adj + E;                        // SCAN_NB (+pad)

    hipMemsetAsync(cnt, 0, NN * sizeof(int), stream);
    hipMemsetAsync(st, 0, 3 * 1024 * sizeof(double), stream);
    hipMemsetAsync(Zb + (size_t)NN * 64, 0, (size_t)(NP - NN) * 64 * sizeof(u16), stream);

    k_counti<<<(E + 255) / 256, 256, 0, stream>>>(dst, E, cnt);
    k_dis<<<(NN + 255) / 256, 256, 0, stream>>>(cnt, dis, NN);
    k_bsum<<<SCAN_NB, 256, 0, stream>>>(cnt, bsum, NN);
    k_scan_bsum<<<1, 256, 0, stream>>>(bsum, SCAN_NB);
    k_scan_fin<<<SCAN_NB, 256, 0, stream>>>(cnt, bsum, rowstart, NN, E);
    hipMemsetAsync(cnt, 0, NN * sizeof(int), stream);
    k_fill<<<(E + 255) / 256, 256, 0, stream>>>(src, dst, E, rowstart, cnt, adj);

    k_wprep<<<(64 * 64 + 255) / 256, 256, 0, stream>>>(W2, 64, Wt2h, Wt2l);
    k_wprep<<<(256 * 64 + 255) / 256, 256, 0, stream>>>(W3, 256, Wt3h, Wt3l);

    const int rows_grid = (NN + 255) / 256;
    const int g16_grid  = (NN + 15) / 16;
    const int wave4_grid = (NN + 3) / 4;
    const int gemm_rows = NP / 64;                 // 782
    const int app_grid = (NN * 16 + 255) / 256;

    // ---- Layer 1 ----
    k_pre3<<<(NN * 3 + 255) / 256, 256, 0, stream>>>(x, dis, P0, NN * 3);
    k_gather3<<<rows_grid, 256, 0, stream>>>(rowstart, adj, P0, dis, Z3, NN);
    k_gemm3_stats<<<gemm_rows, 256, 0, stream>>>(Z3, W1, T, st0, NN);
    k_bn_fin<64><<<1, 64, 0, stream>>>(st0, g1, be1, NN);
    k_apply64<<<app_grid, 256, 0, stream>>>(T, dis, st0, P, NN);

    // ---- Layer 2 ----
    k_gather64_bf16<<<g16_grid, 256, 0, stream>>>(rowstart, adj, P, dis, Zb, NN);
    k_mgemm<<<dim3(gemm_rows, 1), 256, 0, stream>>>(Zb, Wt2h, Wt2l, T, 64, st1, 64);
    k_bn_fin<64><<<1, 64, 0, stream>>>(st1, g2, be2, NN);
    k_apply64<<<app_grid, 256, 0, stream>>>(T, dis, st1, P, NN);

    // ---- Layer 3 ----
    k_gather64_bf16<<<g16_grid, 256, 0, stream>>>(rowstart, adj, P, dis, Zb, NN);
    k_mgemm<<<dim3(gemm_rows, 4), 256, 0, stream>>>(Zb, Wt3h, Wt3l, T, 256, st2, 256);
    k_bn_fin<256><<<1, 256, 0, stream>>>(st2, g3, be3, NN);

    // ---- Layer 3 apply + Layer 4 dot, then scalar gather + sigmoid ----
    k_apply3_dot<<<wave4_grid, 256, 0, stream>>>(T, st2, dis, W4, Q, NN);
    k_gather1_final<<<rows_grid, 256, 0, stream>>>(rowstart, adj, Q, dis, b4, out, NN);
}

// Round 7
// 240.244 us; speedup vs baseline: 2.8315x; 1.4463x over previous
//
#include <hip/hip_runtime.h>
#include <math.h>

#define NN 50000
#define NP 50048   // padded to 64-row multiple (782 * 64)
#define NB (NP / 64)                 // 782 row-blocks
#define SCAN_NB ((NN + 255) / 256)   // 196

typedef unsigned short u16;
typedef unsigned int u32;

typedef __bf16 bf16x8 __attribute__((ext_vector_type(8)));
typedef float f32x4 __attribute__((ext_vector_type(4)));

__device__ __forceinline__ u16 f2bf(float f) {
    u32 u = __float_as_uint(f);
    u32 r = (u + 0x7FFFu + ((u >> 16) & 1u)) >> 16;
    return (u16)r;
}
__device__ __forceinline__ float bf2f_lo(u32 v) { return __uint_as_float(v << 16); }
__device__ __forceinline__ float bf2f_hi(u32 v) { return __uint_as_float(v & 0xFFFF0000u); }

// ---------------- CSR build ----------------
__global__ void k_counti(const int* __restrict__ dst, int E, int* __restrict__ cnt) {
    int i = blockIdx.x * 256 + threadIdx.x;
    if (i < E) atomicAdd(&cnt[dst[i]], 1);
}

__global__ void k_dis(const int* __restrict__ cnt, float* __restrict__ dis, int n) {
    int i = blockIdx.x * 256 + threadIdx.x;
    if (i < n) dis[i] = rsqrtf((float)cnt[i] + 1.0f);
}

__global__ void k_bsum(const int* __restrict__ cnt, int* __restrict__ bsum, int n) {
    __shared__ int sh[256];
    int i = blockIdx.x * 256 + threadIdx.x;
    sh[threadIdx.x] = (i < n) ? cnt[i] : 0;
    __syncthreads();
    for (int off = 128; off; off >>= 1) {
        if (threadIdx.x < off) sh[threadIdx.x] += sh[threadIdx.x + off];
        __syncthreads();
    }
    if (threadIdx.x == 0) bsum[blockIdx.x] = sh[0];
}

__global__ void k_scan_bsum(int* __restrict__ bsum, int nb) {
    __shared__ int sh[256];
    int t = threadIdx.x;
    int v0 = (t < nb) ? bsum[t] : 0;
    sh[t] = v0; __syncthreads();
    int inc = v0;
    for (int off = 1; off < 256; off <<= 1) {
        int o = (t >= off) ? sh[t - off] : 0;
        __syncthreads();
        inc += o; sh[t] = inc;
        __syncthreads();
    }
    if (t < nb) bsum[t] = inc - v0;
}

__global__ void k_scan_fin(const int* __restrict__ cnt, const int* __restrict__ bpre,
                           int* __restrict__ rowstart, int n, int E) {
    __shared__ int sh[256];
    int b = blockIdx.x, t = threadIdx.x;
    int i = b * 256 + t;
    int v0 = (i < n) ? cnt[i] : 0;
    sh[t] = v0; __syncthreads();
    int inc = v0;
    for (int off = 1; off < 256; off <<= 1) {
        int o = (t >= off) ? sh[t - off] : 0;
        __syncthreads();
        inc += o; sh[t] = inc;
        __syncthreads();
    }
    if (i < n) rowstart[i] = bpre[b] + inc - v0;
    if (b == gridDim.x - 1 && t == 0) rowstart[n] = E;
}

__global__ void k_fill(const int* __restrict__ src, const int* __restrict__ dst, int E,
                       const int* __restrict__ rowstart, int* __restrict__ cur,
                       int* __restrict__ adj) {
    int e = blockIdx.x * 256 + threadIdx.x;
    if (e < E) {
        int d = dst[e];
        int p = atomicAdd(&cur[d], 1);
        adj[rowstart[d] + p] = src[e];
    }
}

// ---------------- weight prep ----------------
__global__ void k_wprep(const float* __restrict__ W, int OUT,
                        u16* __restrict__ wth, u16* __restrict__ wtl) {
    int idx = blockIdx.x * 256 + threadIdx.x;
    if (idx >= OUT * 64) return;
    int o = idx >> 6, k = idx & 63;
    float w = W[k * OUT + o];
    u16 h = f2bf(w);
    float hf = __uint_as_float((u32)h << 16);
    u16 l = f2bf(w - hf);
    wth[(size_t)o * 64 + k] = h;
    wtl[(size_t)o * 64 + k] = l;
}

// ---------------- layer-1 front ----------------
__global__ void k_pre3(const float* __restrict__ x, const float* __restrict__ dis,
                       float* __restrict__ p, int n3) {
    int i = blockIdx.x * 256 + threadIdx.x;
    if (i < n3) p[i] = dis[i / 3] * x[i];
}

__global__ void k_gather3(const int* __restrict__ rowstart, const int* __restrict__ adj,
                          const float* __restrict__ p, const float* __restrict__ dis,
                          float* __restrict__ z, int n) {
    int row = blockIdx.x * 256 + threadIdx.x;
    if (row >= n) return;
    float a0 = p[row * 3], a1 = p[row * 3 + 1], a2 = p[row * 3 + 2];
    int beg = rowstart[row], end = rowstart[row + 1];
    for (int j = beg; j < end; j++) {
        int s = adj[j];
        a0 += p[s * 3]; a1 += p[s * 3 + 1]; a2 += p[s * 3 + 2];
    }
    float dv = dis[row];
    z[row * 3] = dv * a0; z[row * 3 + 1] = dv * a1; z[row * 3 + 2] = dv * a2;
}

// ---------------- bf16 gather (64 feats) ----------------
__global__ __launch_bounds__(256) void k_gather64_bf16(const int* __restrict__ rowstart,
        const int* __restrict__ adj, const u16* __restrict__ pb,
        const float* __restrict__ dis, u16* __restrict__ zb, int n) {
    int row = blockIdx.x * 16 + (threadIdx.x >> 4);
    int lane = threadIdx.x & 15;
    if (row >= n) return;
    uint2 v = *((const uint2*)(pb + ((size_t)row << 6)) + lane);
    float a0 = bf2f_lo(v.x), a1 = bf2f_hi(v.x), a2 = bf2f_lo(v.y), a3 = bf2f_hi(v.y);
    int beg = rowstart[row], end = rowstart[row + 1];
    int j = beg;
    for (; j + 3 < end; j += 4) {
        int s0 = adj[j], s1 = adj[j + 1], s2 = adj[j + 2], s3 = adj[j + 3];
        uint2 v0 = *((const uint2*)(pb + ((size_t)s0 << 6)) + lane);
        uint2 v1 = *((const uint2*)(pb + ((size_t)s1 << 6)) + lane);
        uint2 v2 = *((const uint2*)(pb + ((size_t)s2 << 6)) + lane);
        uint2 v3 = *((const uint2*)(pb + ((size_t)s3 << 6)) + lane);
        a0 += (bf2f_lo(v0.x) + bf2f_lo(v1.x)) + (bf2f_lo(v2.x) + bf2f_lo(v3.x));
        a1 += (bf2f_hi(v0.x) + bf2f_hi(v1.x)) + (bf2f_hi(v2.x) + bf2f_hi(v3.x));
        a2 += (bf2f_lo(v0.y) + bf2f_lo(v1.y)) + (bf2f_lo(v2.y) + bf2f_lo(v3.y));
        a3 += (bf2f_hi(v0.y) + bf2f_hi(v1.y)) + (bf2f_hi(v2.y) + bf2f_hi(v3.y));
    }
    for (; j < end; j++) {
        uint2 v0 = *((const uint2*)(pb + ((size_t)adj[j] << 6)) + lane);
        a0 += bf2f_lo(v0.x); a1 += bf2f_hi(v0.x);
        a2 += bf2f_lo(v0.y); a3 += bf2f_hi(v0.y);
    }
    float dv = dis[row];
    uint2 o;
    o.x = (u32)f2bf(a0 * dv) | ((u32)f2bf(a1 * dv) << 16);
    o.y = (u32)f2bf(a2 * dv) | ((u32)f2bf(a3 * dv) << 16);
    ((uint2*)(zb + ((size_t)row << 6)))[lane] = o;
}

__global__ void k_gather1_final(const int* __restrict__ rowstart, const int* __restrict__ adj,
                                const float* __restrict__ q, const float* __restrict__ dis,
                                const float* __restrict__ b4, float* __restrict__ out, int n) {
    int row = blockIdx.x * 256 + threadIdx.x;
    if (row >= n) return;
    float acc = q[row];
    int beg = rowstart[row], end = rowstart[row + 1];
    for (int j = beg; j < end; j++) acc += q[adj[j]];
    float v = dis[row] * acc + b4[0];
    out[row] = 1.f / (1.f + expf(-v));
}

// ---------------- MFMA GEMM + per-block stats partials (no atomics) ----------------
__global__ __launch_bounds__(256) void k_mgemm(const u16* __restrict__ zb,
        const u16* __restrict__ wth, const u16* __restrict__ wtl,
        u16* __restrict__ t, int tstride,
        double* __restrict__ pS, double* __restrict__ pQ) {
    const int wv = threadIdx.x >> 6, lane = threadIdx.x & 63;
    const int lc = lane & 15, lk = lane >> 4;
    const int r0 = blockIdx.x * 64;
    const int col = blockIdx.y * 64 + wv * 16 + lc;

    const bf16x8* wh = (const bf16x8*)(wth + (size_t)col * 64 + lk * 8);
    const bf16x8* wl = (const bf16x8*)(wtl + (size_t)col * 64 + lk * 8);
    bf16x8 bh0 = wh[0], bh1 = wh[4];
    bf16x8 bl0 = wl[0], bl1 = wl[4];

    f32x4 acc[4] = {};
#pragma unroll
    for (int rt = 0; rt < 4; rt++) {
        const bf16x8* ap = (const bf16x8*)(zb + (size_t)(r0 + rt * 16 + lc) * 64 + lk * 8);
        bf16x8 a0 = ap[0], a1 = ap[4];
        acc[rt] = __builtin_amdgcn_mfma_f32_16x16x32_bf16(a0, bh0, acc[rt], 0, 0, 0);
        acc[rt] = __builtin_amdgcn_mfma_f32_16x16x32_bf16(a1, bh1, acc[rt], 0, 0, 0);
        acc[rt] = __builtin_amdgcn_mfma_f32_16x16x32_bf16(a0, bl0, acc[rt], 0, 0, 0);
        acc[rt] = __builtin_amdgcn_mfma_f32_16x16x32_bf16(a1, bl1, acc[rt], 0, 0, 0);
    }
#pragma unroll
    for (int rt = 0; rt < 4; rt++) {
        int rowb = r0 + rt * 16 + lk * 4;
#pragma unroll
        for (int rg = 0; rg < 4; rg++)
            t[(size_t)(rowb + rg) * tstride + col] = f2bf(acc[rt][rg]);
    }
    float s = 0.f, q = 0.f;
#pragma unroll
    for (int rt = 0; rt < 4; rt++)
#pragma unroll
        for (int rg = 0; rg < 4; rg++) { float v = acc[rt][rg]; s += v; q += v * v; }
    s += __shfl_xor(s, 16); q += __shfl_xor(q, 16);
    s += __shfl_xor(s, 32); q += __shfl_xor(q, 32);
    if (lane < 16) {
        pS[(size_t)col * NB + blockIdx.x] = (double)s;
        pQ[(size_t)col * NB + blockIdx.x] = (double)q;
    }
}

// GEMM IN=3 -> OUT=64, bf16 out, stats partials (no atomics)
__global__ __launch_bounds__(256) void k_gemm3_stats(const float* __restrict__ z,
        const float* __restrict__ W, u16* __restrict__ t,
        double* __restrict__ pS, double* __restrict__ pQ, int n) {
    __shared__ float sH[64 * 4];
    __shared__ float sW[3 * 64];
    __shared__ double red[2 * 16 * 64];
    const int tid = threadIdx.x;
    const int r0 = blockIdx.x * 64;
    for (int i = tid; i < 192; i += 256) {
        int r = i / 3, c = i - r * 3;
        sH[r * 4 + c] = (r0 + r < n) ? z[(size_t)(r0 + r) * 3 + c] : 0.f;
    }
    if (tid < 48) ((float4*)sW)[tid] = ((const float4*)W)[tid];
    __syncthreads();
    const int tx = tid & 15, ty = tid >> 4;
    float4 acc[4];
#pragma unroll
    for (int r = 0; r < 4; r++) acc[r] = make_float4(0.f, 0.f, 0.f, 0.f);
    const float4* sW4 = (const float4*)sW;
#pragma unroll
    for (int k = 0; k < 3; k++) {
        float4 wv = sW4[k * 16 + tx];
#pragma unroll
        for (int r = 0; r < 4; r++) {
            float hs = sH[(ty * 4 + r) * 4 + k];
            acc[r].x += hs * wv.x; acc[r].y += hs * wv.y;
            acc[r].z += hs * wv.z; acc[r].w += hs * wv.w;
        }
    }
#pragma unroll
    for (int r = 0; r < 4; r++) {
        int row = r0 + ty * 4 + r;
        if (row < n) {
            uint2 o;
            o.x = (u32)f2bf(acc[r].x) | ((u32)f2bf(acc[r].y) << 16);
            o.y = (u32)f2bf(acc[r].z) | ((u32)f2bf(acc[r].w) << 16);
            *(uint2*)&t[(size_t)row * 64 + tx * 4] = o;
        }
    }
    double* redS = red;
    double* redQ = red + 16 * 64;
    double s0 = 0, s1 = 0, s2 = 0, s3 = 0, q0 = 0, q1 = 0, q2 = 0, q3 = 0;
#pragma unroll
    for (int r = 0; r < 4; r++) {
        s0 += acc[r].x; q0 += (double)acc[r].x * acc[r].x;
        s1 += acc[r].y; q1 += (double)acc[r].y * acc[r].y;
        s2 += acc[r].z; q2 += (double)acc[r].z * acc[r].z;
        s3 += acc[r].w; q3 += (double)acc[r].w * acc[r].w;
    }
    int base = ty * 64 + tx * 4;
    redS[base + 0] = s0; redS[base + 1] = s1; redS[base + 2] = s2; redS[base + 3] = s3;
    redQ[base + 0] = q0; redQ[base + 1] = q1; redQ[base + 2] = q2; redQ[base + 3] = q3;
    __syncthreads();
    if (ty == 0) {
#pragma unroll
        for (int jj = 0; jj < 4; jj++) {
            int c = tx * 4 + jj;
            double S = 0, Q = 0;
            for (int g = 0; g < 16; g++) { S += redS[g * 64 + c]; Q += redQ[g * 64 + c]; }
            pS[(size_t)c * NB + blockIdx.x] = S;
            pQ[(size_t)c * NB + blockIdx.x] = Q;
        }
    }
}

// fused partial-reduce + BN finalize: one block per column
template<int F>
__global__ __launch_bounds__(256) void k_stats_fin(const double* __restrict__ pS,
        const double* __restrict__ pQ, const float* __restrict__ g,
        const float* __restrict__ be, double* __restrict__ st, int n) {
    __shared__ double shS[256], shQ[256];
    int c = blockIdx.x, t = threadIdx.x;
    double s = 0, q = 0;
    for (int i = t; i < NB; i += 256) {
        s += pS[(size_t)c * NB + i];
        q += pQ[(size_t)c * NB + i];
    }
    shS[t] = s; shQ[t] = q;
    __syncthreads();
    for (int off = 128; off; off >>= 1) {
        if (t < off) { shS[t] += shS[t + off]; shQ[t] += shQ[t + off]; }
        __syncthreads();
    }
    if (t == 0) {
        double mean = shS[0] / n;
        double var = shQ[0] / n - mean * mean;
        if (var < 0.0) var = 0.0;
        double mult = (double)g[c] / sqrt(var + 1e-5);
        st[2 * F + c] = mult;
        st[3 * F + c] = (double)be[c] - mult * mean;
    }
}

// p_bf16 = dis[v] * lrelu(mult*t_bf16 + add)   (F=64)
__global__ void k_apply64(const u16* __restrict__ t, const float* __restrict__ dis,
                          const double* __restrict__ st, u16* __restrict__ p, int n) {
    int idx = blockIdx.x * 256 + threadIdx.x;
    if (idx >= n * 16) return;
    int row = idx >> 4, c = (idx & 15) * 4;
    uint2 v = ((const uint2*)t)[idx];
    float f0 = bf2f_lo(v.x), f1 = bf2f_hi(v.x), f2 = bf2f_lo(v.y), f3 = bf2f_hi(v.y);
    float m0 = (float)st[128 + c], m1 = (float)st[129 + c],
          m2 = (float)st[130 + c], m3 = (float)st[131 + c];
    float a0 = (float)st[192 + c], a1 = (float)st[193 + c],
          a2 = (float)st[194 + c], a3 = (float)st[195 + c];
    float r0 = m0 * f0 + a0; r0 = r0 > 0.f ? r0 : 0.1f * r0;
    float r1 = m1 * f1 + a1; r1 = r1 > 0.f ? r1 : 0.1f * r1;
    float r2 = m2 * f2 + a2; r2 = r2 > 0.f ? r2 : 0.1f * r2;
    float r3 = m3 * f3 + a3; r3 = r3 > 0.f ? r3 : 0.1f * r3;
    float dv = dis[row];
    uint2 o;
    o.x = (u32)f2bf(r0 * dv) | ((u32)f2bf(r1 * dv) << 16);
    o.y = (u32)f2bf(r2 * dv) | ((u32)f2bf(r3 * dv) << 16);
    ((uint2*)p)[idx] = o;
}

// layer3 apply + layer4 dot fused (t bf16, stride 256)
__global__ void k_apply3_dot(const u16* __restrict__ t, const double* __restrict__ st,
                             const float* __restrict__ dis, const float* __restrict__ W4,
                             float* __restrict__ q, int n) {
    int row = blockIdx.x * 4 + (threadIdx.x >> 6);
    int lane = threadIdx.x & 63;
    if (row >= n) return;
    uint2 v = ((const uint2*)t)[(size_t)row * 64 + lane];
    float f0 = bf2f_lo(v.x), f1 = bf2f_hi(v.x), f2 = bf2f_lo(v.y), f3 = bf2f_hi(v.y);
    int c = lane * 4;
    float m0 = (float)st[512 + c], m1 = (float)st[513 + c],
          m2 = (float)st[514 + c], m3 = (float)st[515 + c];
    float a0 = (float)st[768 + c], a1 = (float)st[769 + c],
          a2 = (float)st[770 + c], a3 = (float)st[771 + c];
    float b0 = m0 * f0 + a0; b0 = b0 > 0.f ? b0 : 0.1f * b0;
    float b1 = m1 * f1 + a1; b1 = b1 > 0.f ? b1 : 0.1f * b1;
    float b2 = m2 * f2 + a2; b2 = b2 > 0.f ? b2 : 0.1f * b2;
    float b3 = m3 * f3 + a3; b3 = b3 > 0.f ? b3 : 0.1f * b3;
    float4 w = ((const float4*)W4)[lane];
    float s = b0 * w.x + b1 * w.y + b2 * w.z + b3 * w.w;
#pragma unroll
    for (int off = 32; off; off >>= 1) s += __shfl_down(s, off);
    if (lane == 0) q[row] = dis[row] * s;
}

extern "C" void kernel_launch(void* const* d_in, const int* in_sizes, int n_in,
                              void* d_out, int out_size, void* d_ws, size_t ws_size,
                              hipStream_t stream) {
    const float* x  = (const float*)d_in[0];
    const int*   ei = (const int*)d_in[1];
    const int E = in_sizes[1] / 2;
    const int* src = ei;
    const int* dst = ei + E;
    const float* W1 = (const float*)d_in[2];
    const float* g1 = (const float*)d_in[4];
    const float* be1= (const float*)d_in[5];
    const float* W2 = (const float*)d_in[6];
    const float* g2 = (const float*)d_in[8];
    const float* be2= (const float*)d_in[9];
    const float* W3 = (const float*)d_in[10];
    const float* g3 = (const float*)d_in[12];
    const float* be3= (const float*)d_in[13];
    const float* W4 = (const float*)d_in[14];
    const float* b4 = (const float*)d_in[15];
    float* out = (float*)d_out;

    // workspace layout
    u16*   T    = (u16*)d_ws;                       // NP*256 bf16
    u16*   P    = T + (size_t)NP * 256;             // NN*64  bf16
    u16*   Zb   = P + (size_t)NN * 64;              // NP*64  bf16 (pad rows zeroed)
    u16*   Wt2h = Zb + (size_t)NP * 64;             // 64*64
    u16*   Wt2l = Wt2h + 64 * 64;                   // 64*64
    u16*   Wt3h = Wt2l + 64 * 64;                   // 256*64
    u16*   Wt3l = Wt3h + 256 * 64;                  // 256*64
    double* st  = (double*)(Wt3l + 256 * 64);       // 3*1024 doubles (mult/add slots)
    double *st0 = st, *st1 = st + 1024, *st2 = st + 2048;
    double* pS  = st + 3 * 1024;                    // 256*NB
    double* pQ  = pS + (size_t)256 * NB;            // 256*NB
    float* Z3   = (float*)(pQ + (size_t)256 * NB);  // NN*3
    float* P0   = Z3 + NN * 3;                      // NN*3
    float* Q    = P0 + NN * 3;                      // NN
    float* dis  = Q + NN;                           // NN
    int* cnt      = (int*)(dis + NN);               // NN
    int* rowstart = cnt + NN;                       // NN+1 (+pad)
    int* adj      = rowstart + NN + 8;              // E
    int* bsum     = adj + E;                        // SCAN_NB

    hipMemsetAsync(cnt, 0, NN * sizeof(int), stream);
    hipMemsetAsync(Zb + (size_t)NN * 64, 0, (size_t)(NP - NN) * 64 * sizeof(u16), stream);

    k_counti<<<(E + 255) / 256, 256, 0, stream>>>(dst, E, cnt);
    k_dis<<<(NN + 255) / 256, 256, 0, stream>>>(cnt, dis, NN);
    k_bsum<<<SCAN_NB, 256, 0, stream>>>(cnt, bsum, NN);
    k_scan_bsum<<<1, 256, 0, stream>>>(bsum, SCAN_NB);
    k_scan_fin<<<SCAN_NB, 256, 0, stream>>>(cnt, bsum, rowstart, NN, E);
    hipMemsetAsync(cnt, 0, NN * sizeof(int), stream);
    k_fill<<<(E + 255) / 256, 256, 0, stream>>>(src, dst, E, rowstart, cnt, adj);

    k_wprep<<<(64 * 64 + 255) / 256, 256, 0, stream>>>(W2, 64, Wt2h, Wt2l);
    k_wprep<<<(256 * 64 + 255) / 256, 256, 0, stream>>>(W3, 256, Wt3h, Wt3l);

    const int rows_grid = (NN + 255) / 256;
    const int g16_grid  = (NN + 15) / 16;
    const int wave4_grid = (NN + 3) / 4;
    const int app_grid = (NN * 16 + 255) / 256;

    // ---- Layer 1 ----
    k_pre3<<<(NN * 3 + 255) / 256, 256, 0, stream>>>(x, dis, P0, NN * 3);
    k_gather3<<<rows_grid, 256, 0, stream>>>(rowstart, adj, P0, dis, Z3, NN);
    k_gemm3_stats<<<NB, 256, 0, stream>>>(Z3, W1, T, pS, pQ, NN);
    k_stats_fin<64><<<64, 256, 0, stream>>>(pS, pQ, g1, be1, st0, NN);
    k_apply64<<<app_grid, 256, 0, stream>>>(T, dis, st0, P, NN);

    // ---- Layer 2 ----
    k_gather64_bf16<<<g16_grid, 256, 0, stream>>>(rowstart, adj, P, dis, Zb, NN);
    k_mgemm<<<dim3(NB, 1), 256, 0, stream>>>(Zb, Wt2h, Wt2l, T, 64, pS, pQ);
    k_stats_fin<64><<<64, 256, 0, stream>>>(pS, pQ, g2, be2, st1, NN);
    k_apply64<<<app_grid, 256, 0, stream>>>(T, dis, st1, P, NN);

    // ---- Layer 3 ----
    k_gather64_bf16<<<g16_grid, 256, 0, stream>>>(rowstart, adj, P, dis, Zb, NN);
    k_mgemm<<<dim3(NB, 4), 256, 0, stream>>>(Zb, Wt3h, Wt3l, T, 256, pS, pQ);
    k_stats_fin<256><<<256, 256, 0, stream>>>(pS, pQ, g3, be3, st2, NN);

    // ---- Layer 3 apply + Layer 4 dot, then scalar gather + sigmoid ----
    k_apply3_dot<<<wave4_grid, 256, 0, stream>>>(T, st2, dis, W4, Q, NN);
    k_gather1_final<<<rows_grid, 256, 0, stream>>>(rowstart, adj, Q, dis, b4, out, NN);
}